// Round 15
// baseline (423.037 us; speedup 1.0000x reference)
//
#include <hip/hip_runtime.h>
#include <hip/hip_bf16.h>

typedef unsigned int uint32;

// ---------------------------------------------------------------------------
// Graph preprocessing: degree count (+ per-edge rank) -> hierarchical scan
// ---------------------------------------------------------------------------

// rank[e] = position of edge e within its target node's CSR segment.
__global__ __launch_bounds__(256)
void count_rank_kernel(const int* __restrict__ col, int n_edges,
                       uint32* __restrict__ cnt, uint32* __restrict__ rank) {
    int e = blockIdx.x * 256 + threadIdx.x;
    if (e < n_edges) rank[e] = atomicAdd(&cnt[col[e]], 1u);
}

// Stage 1: per-block (256 elems) exclusive scan + per-block sum.
__global__ __launch_bounds__(256)
void scan_blk_kernel(const uint32* __restrict__ cnt, uint32* __restrict__ partial,
                     uint32* __restrict__ blk_sums, int n) {
    __shared__ uint32 sh[256];
    int i = blockIdx.x * 256 + (int)threadIdx.x;
    uint32 v = (i < n) ? cnt[i] : 0u;
    sh[threadIdx.x] = v;
    __syncthreads();
    for (int off = 1; off < 256; off <<= 1) {
        uint32 t = (threadIdx.x >= (unsigned)off) ? sh[threadIdx.x - off] : 0u;
        __syncthreads();
        sh[threadIdx.x] += t;
        __syncthreads();
    }
    if (i < n) partial[i] = sh[threadIdx.x] - v;      // exclusive within block
    if (threadIdx.x == 255) blk_sums[blockIdx.x] = sh[255];
}

// Stage 2: one block scans the block sums (nb <= 1024).
__global__ __launch_bounds__(1024)
void scan_sums_kernel(const uint32* __restrict__ blk_sums, uint32* __restrict__ blk_offs, int nb) {
    __shared__ uint32 sh[1024];
    uint32 v = ((int)threadIdx.x < nb) ? blk_sums[threadIdx.x] : 0u;
    sh[threadIdx.x] = v;
    __syncthreads();
    for (int off = 1; off < 1024; off <<= 1) {
        uint32 t = (threadIdx.x >= (unsigned)off) ? sh[threadIdx.x - off] : 0u;
        __syncthreads();
        sh[threadIdx.x] += t;
        __syncthreads();
    }
    if ((int)threadIdx.x < nb) blk_offs[threadIdx.x] = sh[threadIdx.x] - v;
}

// Stage 3: offs = partial + blk_offs; fused dis = rsqrt(deg+1).
__global__ __launch_bounds__(256)
void scan_add_kernel(const uint32* __restrict__ partial, const uint32* __restrict__ blk_offs,
                     const uint32* __restrict__ cnt, uint32* __restrict__ offs,
                     float* __restrict__ dis, int n, int n_edges) {
    int i = blockIdx.x * 256 + (int)threadIdx.x;
    if (i < n) {
        offs[i] = partial[i] + blk_offs[blockIdx.x];
        dis[i] = rsqrtf((float)(cnt[i] + 1u));   // self-loop => deg >= 1
    }
    if (i == 0) offs[n] = (uint32)n_edges;       // sum of cnt == n_edges
}

// ---------------------------------------------------------------------------
// bf16 helpers (RNE, deterministic)
// ---------------------------------------------------------------------------
static __device__ __forceinline__ uint32 f32_to_bf16_rne(float f) {
    uint32 u = __float_as_uint(f);
    return (u + 0x7fffu + ((u >> 16) & 1u)) >> 16;
}
static __device__ __forceinline__ float bf16_lo(uint32 v) {   // feats 2*lane
    return __uint_as_float(v << 16);
}
static __device__ __forceinline__ float bf16_hi(uint32 v) {   // feats 2*lane+1
    return __uint_as_float(v & 0xffff0000u);
}

// ---------------------------------------------------------------------------
// GEMM body: hs[r][c] = dis[r] * sum_k A[gather(r)][k] * W[k][c]  (PRE-SCALED:
// the per-edge dis[row] factor is folded into the stored row, so the gather
// loops do pure load+add). Packed-bf16 output (row = 256B).
// 4 rows x 8 cols per thread; 64 rows per 256-thread block.
// ---------------------------------------------------------------------------
static __device__ __forceinline__
void gemm_body(int gbid, const float* __restrict__ A, const int* __restrict__ gather,
               const float* __restrict__ W0, const float* __restrict__ W1b,
               int wstride, const float* __restrict__ dis,
               uint32* __restrict__ out, int n_rows) {
    int grp = threadIdx.x >> 4;            // 0..15
    int c8  = (threadIdx.x & 15) * 8;      // col block
    int r0  = gbid * 64 + grp * 4;         // first of 4 rows
    if (r0 >= n_rows) return;

    const float* wb = (c8 < 64) ? (W0 + c8) : (W1b + (c8 - 64));

    const float* ap[4];
    #pragma unroll
    for (int i = 0; i < 4; i++) {
        int r = r0 + i;
        if (r > n_rows - 1) r = n_rows - 1;
        int ra = gather ? gather[r] : r;
        ap[i] = A + (size_t)ra * 128;
    }

    float acc[4][8];
    #pragma unroll
    for (int i = 0; i < 4; i++)
        #pragma unroll
        for (int j = 0; j < 8; j++) acc[i][j] = 0.f;

    for (int k = 0; k < 128; k += 4) {
        float4 av[4];
        #pragma unroll
        for (int i = 0; i < 4; i++) av[i] = *(const float4*)(ap[i] + k);

        const float* w = wb + (size_t)k * wstride;
        #pragma unroll
        for (int kk = 0; kk < 4; kk++) {
            float4 w0 = *(const float4*)(w);
            float4 w1 = *(const float4*)(w + 4);
            #pragma unroll
            for (int i = 0; i < 4; i++) {
                float s = (kk == 0) ? av[i].x : (kk == 1) ? av[i].y
                        : (kk == 2) ? av[i].z : av[i].w;
                acc[i][0] = fmaf(s, w0.x, acc[i][0]);
                acc[i][1] = fmaf(s, w0.y, acc[i][1]);
                acc[i][2] = fmaf(s, w0.z, acc[i][2]);
                acc[i][3] = fmaf(s, w0.w, acc[i][3]);
                acc[i][4] = fmaf(s, w1.x, acc[i][4]);
                acc[i][5] = fmaf(s, w1.y, acc[i][5]);
                acc[i][6] = fmaf(s, w1.z, acc[i][6]);
                acc[i][7] = fmaf(s, w1.w, acc[i][7]);
            }
            w += wstride;
        }
    }

    #pragma unroll
    for (int i = 0; i < 4; i++) {
        int r = r0 + i;
        if (r < n_rows) {
            float d = dis[r];
            uint4 pk;
            pk.x = f32_to_bf16_rne(d * acc[i][0]) | (f32_to_bf16_rne(d * acc[i][1]) << 16);
            pk.y = f32_to_bf16_rne(d * acc[i][2]) | (f32_to_bf16_rne(d * acc[i][3]) << 16);
            pk.z = f32_to_bf16_rne(d * acc[i][4]) | (f32_to_bf16_rne(d * acc[i][5]) << 16);
            pk.w = f32_to_bf16_rne(d * acc[i][6]) | (f32_to_bf16_rne(d * acc[i][7]) << 16);
            *(uint4*)(out + (size_t)r * 64 + (c8 >> 1)) = pk;
        }
    }
}

// ---------------------------------------------------------------------------
// Fused: CSR fill (pure scatter, NO atomics — rank precomputed) + layer-1 GEMM.
// Role-interleaved blocks (every 9th = gemm) keep both populations co-resident.
// ---------------------------------------------------------------------------
__global__ __launch_bounds__(256)
void fill_gemm_kernel(const int* __restrict__ row, const int* __restrict__ col,
                      const uint32* __restrict__ rank, int n_edges,
                      const uint32* __restrict__ offs, uint32* __restrict__ csr,
                      const float* __restrict__ A, const int* __restrict__ gather,
                      const float* __restrict__ W0, const float* __restrict__ W1b,
                      int wstride, const float* __restrict__ dis,
                      uint32* __restrict__ out, int n_rows, int n_gemm_blocks) {
    int bid = blockIdx.x;
    int q = bid / 9, r = bid % 9;
    bool is_gemm = (r == 0) && (q < n_gemm_blocks);
    if (is_gemm) {
        gemm_body(q, A, gather, W0, W1b, wstride, dis, out, n_rows);
    } else {
        int before = q + (r ? 1 : 0);
        if (before > n_gemm_blocks) before = n_gemm_blocks;
        int fid = bid - before;
        int e = fid * 256 + (int)threadIdx.x;
        if (e < n_edges) {
            int c = col[e];
            csr[offs[c] + rank[e]] = (uint32)row[e];
        }
    }
}

// ---------------------------------------------------------------------------
// Fused layer-1 aggregation + layer-2 GEMM. 32 nodes per 256-thread block.
// hs rows are PRE-SCALED by dis[row] -> gather loop is pure load+add.
// Phase 1: one wave per node (8 sequential nodes/wave): gather bf16 hs rows,
//   h1 = relu(dis[v]*(self+agg)+b1) -> LDS [32][132] f32 (pad kills conflicts).
// Phase 2: h2 = dis[r] * (h1 @ [Wmu|Wlv]) (2 rows x 8 cols/thread, PRE-SCALED
//   for the next gather), bf16-pack -> out.
// ---------------------------------------------------------------------------
__global__ __launch_bounds__(256)
void agg1_gemm2_kernel(const uint32* __restrict__ hs, const uint32* __restrict__ offs,
                       const uint32* __restrict__ csr, const float* __restrict__ dis,
                       const float* __restrict__ b1,
                       const float* __restrict__ Wmu, const float* __restrict__ Wlv,
                       uint32* __restrict__ out, int n_nodes) {
    __shared__ float h1[32][132];
    int wave = threadIdx.x >> 6;
    int lane = threadIdx.x & 63;
    int base = blockIdx.x * 32;

    // ---- Phase 1: gather + relu, 8 nodes per wave ----
    for (int i = 0; i < 8; i++) {
        int nl = wave * 8 + i;
        int wid = base + nl;
        float ax = 0.f, ay = 0.f;
        if (wid < n_nodes) {
            uint32 sv = hs[(size_t)wid * 64 + lane];        // self-loop (pre-scaled)
            ax = bf16_lo(sv); ay = bf16_hi(sv);
            int beg = (int)offs[wid], end = (int)offs[wid + 1];
            int j = beg;
            for (; j + 8 <= end; j += 8) {
                uint32 e0 = csr[j],     e1 = csr[j + 1], e2 = csr[j + 2], e3 = csr[j + 3];
                uint32 e4 = csr[j + 4], e5 = csr[j + 5], e6 = csr[j + 6], e7 = csr[j + 7];
                uint32 v0 = hs[(size_t)e0 * 64 + lane];
                uint32 v1 = hs[(size_t)e1 * 64 + lane];
                uint32 v2 = hs[(size_t)e2 * 64 + lane];
                uint32 v3 = hs[(size_t)e3 * 64 + lane];
                uint32 v4 = hs[(size_t)e4 * 64 + lane];
                uint32 v5 = hs[(size_t)e5 * 64 + lane];
                uint32 v6 = hs[(size_t)e6 * 64 + lane];
                uint32 v7 = hs[(size_t)e7 * 64 + lane];
                float sx = ((bf16_lo(v0) + bf16_lo(v1)) + (bf16_lo(v2) + bf16_lo(v3)))
                         + ((bf16_lo(v4) + bf16_lo(v5)) + (bf16_lo(v6) + bf16_lo(v7)));
                float sy = ((bf16_hi(v0) + bf16_hi(v1)) + (bf16_hi(v2) + bf16_hi(v3)))
                         + ((bf16_hi(v4) + bf16_hi(v5)) + (bf16_hi(v6) + bf16_hi(v7)));
                ax += sx; ay += sy;
            }
            for (; j < end; ++j) {
                uint32 v = hs[(size_t)csr[j] * 64 + lane];
                ax += bf16_lo(v); ay += bf16_hi(v);
            }
            float dv = dis[wid];
            float2 b = ((const float2*)b1)[lane];
            ax = fmaxf(fmaf(dv, ax, b.x), 0.f);
            ay = fmaxf(fmaf(dv, ay, b.y), 0.f);
        }
        *(float2*)&h1[nl][2 * lane] = make_float2(ax, ay);
    }
    __syncthreads();

    // ---- Phase 2: h2 = dis * (h1 @ [Wmu|Wlv]), pack bf16 ----
    int rgrp = threadIdx.x >> 4;          // 0..15 -> rows 2*rgrp, 2*rgrp+1
    int c8   = (threadIdx.x & 15) * 8;    // col block
    const float* wb = (c8 < 64) ? (Wmu + c8) : (Wlv + (c8 - 64));

    float acc[2][8];
    #pragma unroll
    for (int i = 0; i < 2; i++)
        #pragma unroll
        for (int j = 0; j < 8; j++) acc[i][j] = 0.f;

    for (int k = 0; k < 128; k += 4) {
        float4 av0 = *(const float4*)&h1[2 * rgrp][k];
        float4 av1 = *(const float4*)&h1[2 * rgrp + 1][k];
        const float* w = wb + (size_t)k * 64;
        #pragma unroll
        for (int kk = 0; kk < 4; kk++) {
            float4 w0 = *(const float4*)(w);
            float4 w1 = *(const float4*)(w + 4);
            float s0 = (kk == 0) ? av0.x : (kk == 1) ? av0.y : (kk == 2) ? av0.z : av0.w;
            float s1 = (kk == 0) ? av1.x : (kk == 1) ? av1.y : (kk == 2) ? av1.z : av1.w;
            acc[0][0] = fmaf(s0, w0.x, acc[0][0]); acc[1][0] = fmaf(s1, w0.x, acc[1][0]);
            acc[0][1] = fmaf(s0, w0.y, acc[0][1]); acc[1][1] = fmaf(s1, w0.y, acc[1][1]);
            acc[0][2] = fmaf(s0, w0.z, acc[0][2]); acc[1][2] = fmaf(s1, w0.z, acc[1][2]);
            acc[0][3] = fmaf(s0, w0.w, acc[0][3]); acc[1][3] = fmaf(s1, w0.w, acc[1][3]);
            acc[0][4] = fmaf(s0, w1.x, acc[0][4]); acc[1][4] = fmaf(s1, w1.x, acc[1][4]);
            acc[0][5] = fmaf(s0, w1.y, acc[0][5]); acc[1][5] = fmaf(s1, w1.y, acc[1][5]);
            acc[0][6] = fmaf(s0, w1.z, acc[0][6]); acc[1][6] = fmaf(s1, w1.z, acc[1][6]);
            acc[0][7] = fmaf(s0, w1.w, acc[0][7]); acc[1][7] = fmaf(s1, w1.w, acc[1][7]);
            w += 64;
        }
    }

    #pragma unroll
    for (int i = 0; i < 2; i++) {
        int r = base + 2 * rgrp + i;
        if (r < n_nodes) {
            float d = dis[r];
            uint4 pk;
            pk.x = f32_to_bf16_rne(d * acc[i][0]) | (f32_to_bf16_rne(d * acc[i][1]) << 16);
            pk.y = f32_to_bf16_rne(d * acc[i][2]) | (f32_to_bf16_rne(d * acc[i][3]) << 16);
            pk.z = f32_to_bf16_rne(d * acc[i][4]) | (f32_to_bf16_rne(d * acc[i][5]) << 16);
            pk.w = f32_to_bf16_rne(d * acc[i][6]) | (f32_to_bf16_rne(d * acc[i][7]) << 16);
            *(uint4*)(out + (size_t)r * 64 + (c8 >> 1)) = pk;
        }
    }
}

// Layer 2 aggregation over PRE-SCALED h2 rows: pure load+add gather.
// feats 0..63 -> mu (+b_mu), 64..127 -> logvar (+b_logvar).
__global__ __launch_bounds__(256)
void agg_out_kernel(const uint32* __restrict__ hs, const uint32* __restrict__ offs,
                    const uint32* __restrict__ csr, const float* __restrict__ dis,
                    const float* __restrict__ bmu, const float* __restrict__ blv,
                    float* __restrict__ out_mu, float* __restrict__ out_lv, int n_nodes) {
    int wid = (blockIdx.x * 256 + (int)threadIdx.x) >> 6;
    int lane = threadIdx.x & 63;
    if (wid >= n_nodes) return;

    uint32 sv = hs[(size_t)wid * 64 + lane];    // self-loop (pre-scaled)
    float ax = bf16_lo(sv), ay = bf16_hi(sv);
    int beg = (int)offs[wid], end = (int)offs[wid + 1];

    int j = beg;
    for (; j + 8 <= end; j += 8) {
        uint32 e0 = csr[j],     e1 = csr[j + 1], e2 = csr[j + 2], e3 = csr[j + 3];
        uint32 e4 = csr[j + 4], e5 = csr[j + 5], e6 = csr[j + 6], e7 = csr[j + 7];
        uint32 v0 = hs[(size_t)e0 * 64 + lane];
        uint32 v1 = hs[(size_t)e1 * 64 + lane];
        uint32 v2 = hs[(size_t)e2 * 64 + lane];
        uint32 v3 = hs[(size_t)e3 * 64 + lane];
        uint32 v4 = hs[(size_t)e4 * 64 + lane];
        uint32 v5 = hs[(size_t)e5 * 64 + lane];
        uint32 v6 = hs[(size_t)e6 * 64 + lane];
        uint32 v7 = hs[(size_t)e7 * 64 + lane];
        float sx = ((bf16_lo(v0) + bf16_lo(v1)) + (bf16_lo(v2) + bf16_lo(v3)))
                 + ((bf16_lo(v4) + bf16_lo(v5)) + (bf16_lo(v6) + bf16_lo(v7)));
        float sy = ((bf16_hi(v0) + bf16_hi(v1)) + (bf16_hi(v2) + bf16_hi(v3)))
                 + ((bf16_hi(v4) + bf16_hi(v5)) + (bf16_hi(v6) + bf16_hi(v7)));
        ax += sx; ay += sy;
    }
    for (; j < end; ++j) {
        uint32 v = hs[(size_t)csr[j] * 64 + lane];
        ax += bf16_lo(v); ay += bf16_hi(v);
    }

    float dv = dis[wid];
    if (lane < 32) {
        float2 b = ((const float2*)bmu)[lane];
        float2 o = make_float2(fmaf(dv, ax, b.x), fmaf(dv, ay, b.y));
        ((float2*)out_mu)[(size_t)wid * 32 + lane] = o;
    } else {
        int l2 = lane - 32;
        float2 b = ((const float2*)blv)[l2];
        float2 o = make_float2(fmaf(dv, ax, b.x), fmaf(dv, ay, b.y));
        ((float2*)out_lv)[(size_t)wid * 32 + l2] = o;
    }
}

// ---------------------------------------------------------------------------

extern "C" void kernel_launch(void* const* d_in, const int* in_sizes, int n_in,
                              void* d_out, int out_size, void* d_ws, size_t ws_size,
                              hipStream_t stream) {
    const int*   x   = (const int*)d_in[0];
    const int*   ei  = (const int*)d_in[1];
    const float* emb = (const float*)d_in[2];
    const float* W1  = (const float*)d_in[3];
    const float* b1  = (const float*)d_in[4];
    const float* Wmu = (const float*)d_in[5];
    const float* bmu = (const float*)d_in[6];
    const float* Wlv = (const float*)d_in[7];
    const float* blv = (const float*)d_in[8];

    int n_nodes = in_sizes[0];
    int n_edges = in_sizes[1] / 2;
    const int* row = ei;              // source nodes
    const int* col = ei + n_edges;    // target nodes (aggregation index)

    // Workspace carve-out (all 256B-aligned).
    char* wp = (char*)d_ws;
    auto carve = [&wp](size_t bytes) -> char* {
        char* p = wp;
        wp += (bytes + 255) & ~(size_t)255;
        return p;
    };
    int nb = (n_nodes + 255) / 256;   // scan blocks (196 for 50k, <= 1024)

    uint32* cnt     = (uint32*)carve((size_t)n_nodes * 4);
    uint32* offs    = (uint32*)carve(((size_t)n_nodes + 1) * 4);
    uint32* partial = (uint32*)carve((size_t)n_nodes * 4);
    uint32* bsums   = (uint32*)carve((size_t)nb * 4);
    uint32* boffs   = (uint32*)carve((size_t)nb * 4);
    float*  dis     = (float*) carve((size_t)n_nodes * 4);
    uint32* rank    = (uint32*)carve((size_t)n_edges * 4);
    uint32* csr     = (uint32*)carve((size_t)n_edges * 4);
    uint32* bufA    = (uint32*)carve((size_t)n_nodes * 64 * 4);    // hs, packed bf16
    uint32* bufC    = (uint32*)carve((size_t)n_nodes * 64 * 4);    // h2, packed bf16

    int gb_e = (n_edges + 255) / 256;            // fill blocks (6250)
    int gemm_blocks = (n_nodes + 63) / 64;       // 782
    int agg_blocks  = (n_nodes + 3) / 4;
    int ag_blocks   = (n_nodes + 31) / 32;       // fused agg1+gemm2 blocks

    hipMemsetAsync(cnt, 0, (size_t)n_nodes * 4, stream);
    hipLaunchKernelGGL(count_rank_kernel, dim3(gb_e), dim3(256), 0, stream,
                       col, n_edges, cnt, rank);
    hipLaunchKernelGGL(scan_blk_kernel, dim3(nb), dim3(256), 0, stream, cnt, partial, bsums, n_nodes);
    hipLaunchKernelGGL(scan_sums_kernel, dim3(1), dim3(1024), 0, stream, bsums, boffs, nb);
    hipLaunchKernelGGL(scan_add_kernel, dim3(nb), dim3(256), 0, stream,
                       partial, boffs, cnt, offs, dis, n_nodes, n_edges);

    // Fused: CSR fill (atomic-free scatter) + layer-1 GEMM
    // (hs = bf16(dis * (emb[x] @ W1)), pre-scaled for the gathers)
    hipLaunchKernelGGL(fill_gemm_kernel, dim3(gb_e + gemm_blocks), dim3(256), 0, stream,
                       row, col, rank, n_edges, offs, csr,
                       emb, x, W1, W1 + 64, 128, dis, bufA, n_nodes, gemm_blocks);

    // Fused: layer-1 aggregation + relu + layer-2 GEMM (bufA -> bufC, pre-scaled)
    hipLaunchKernelGGL(agg1_gemm2_kernel, dim3(ag_blocks), dim3(256), 0, stream,
                       bufA, offs, csr, dis, b1, Wmu, Wlv, bufC, n_nodes);

    float* out_mu = (float*)d_out;
    float* out_lv = out_mu + (size_t)n_nodes * 64;
    hipLaunchKernelGGL(agg_out_kernel, dim3(agg_blocks), dim3(256), 0, stream,
                       bufC, offs, csr, dis, bmu, blv, out_mu, out_lv, n_nodes);
}